// Round 5
// baseline (31379.214 us; speedup 1.0000x reference)
//
#include <hip/hip_runtime.h>

#define T_   2048
#define NWG  32

typedef float  float4v __attribute__((ext_vector_type(4)));
typedef float  float2v __attribute__((ext_vector_type(2)));
typedef short  short8v __attribute__((ext_vector_type(8)));
typedef unsigned uint4v __attribute__((ext_vector_type(4)));
typedef unsigned short ushort_t;

__device__ __forceinline__ ushort_t f2bf(float f) {
  union { float f; unsigned u; } v; v.f = f;
  unsigned r = (v.u + 0x7FFFu + ((v.u >> 16) & 1u)) >> 16;  // RTN
  return (ushort_t)r;
}
__device__ __forceinline__ float sigm(float x) {
  x = fmaxf(x, -30.f);
  return __fdividef(1.f, 1.f + __expf(-x));
}
__device__ __forceinline__ float tanh_(float x) {
  x = fminf(fmaxf(x, -15.f), 15.f);
  float e = __expf(2.f * x);
  return (e - 1.f) * __fdividef(1.f, e + 1.f);
}

// L2-coherent (same-XCD) ops: sc0 = bypass L1, hit the XCD-shared L2.
// Inline-asm vmem is NOT tracked by compiler waitcnt — wait manually.
__device__ __forceinline__ short8v ld_l2_16(const ushort_t* p) {
  short8v r;
  asm volatile("global_load_dwordx4 %0, %1, off sc0" : "=v"(r) : "v"(p));
  return r;
}
__device__ __forceinline__ void st_l2_u32(void* p, unsigned v) {
  asm volatile("global_store_dword %0, %1, off sc0" :: "v"(p), "v"(v) : "memory");
}

// W1[n,k] = sum_j W_hh[n,j] * W_hs[j,k]   (fold: h2 @ W_hh^T == h_new @ W1^T)
__global__ void k_prep_w1(const float* __restrict__ Whh, const float* __restrict__ Whs,
                          ushort_t* __restrict__ w1) {
  int idx = blockIdx.x * 256 + threadIdx.x;
  if (idx >= 2048 * 512) return;
  int n = idx >> 9, k = idx & 511;
  const float* whr = Whh + (size_t)n * 512;
  const float* wsk = Whs + k;
  float s = 0.f;
  #pragma unroll 8
  for (int j = 0; j < 512; ++j) s += whr[j] * wsk[(size_t)j * 512];
  w1[idx] = f2bf(s);
}

__global__ void k_prep_misc(const float* __restrict__ Wih, const float* __restrict__ Wcs,
                            const float* __restrict__ Whs, const float* __restrict__ bih,
                            const float* __restrict__ bhh,
                            ushort_t* __restrict__ wih_bf, ushort_t* __restrict__ wcs_bf,
                            ushort_t* __restrict__ whs_bf, float* __restrict__ bias,
                            ushort_t* __restrict__ HN, ushort_t* __restrict__ CN,
                            int* __restrict__ flags, int* __restrict__ claim) {
  const int total = 1048576 + 262144 + 262144 + 2048 + 16384 + 16384 + 32 + 9;
  for (int i = blockIdx.x * blockDim.x + threadIdx.x; i < total; i += gridDim.x * blockDim.x) {
    int r = i;
    if (r < 1048576) { wih_bf[r] = f2bf(Wih[r]); continue; }
    r -= 1048576;
    if (r < 262144)  { wcs_bf[r] = f2bf(Wcs[r]); continue; }
    r -= 262144;
    if (r < 262144)  { whs_bf[r] = f2bf(Whs[r]); continue; }
    r -= 262144;
    if (r < 2048)    { bias[r] = bih[r] + bhh[r]; continue; }
    r -= 2048;
    if (r < 16384)   { HN[3 * 16384 + r] = 0; continue; }   // zero ring slot 3 (state t=-1)
    r -= 16384;
    if (r < 16384)   { CN[3 * 16384 + r] = 0; continue; }
    r -= 16384;
    if (r < 32)      { flags[r] = 0; continue; }
    r -= 32;
    claim[r] = (r == 8) ? -1 : 0;   // claim[0..7]=per-XCD counters, claim[8]=winner
  }
}

// Persistent recurrent kernel. 512 WGs launched; the 32 that land on the
// winning XCD claim fb=0..31 and run the recurrence communicating through
// that XCD's shared L2 (sc0 ops). Everyone else exits immediately.
__global__ __launch_bounds__(256, 1) void k_lstm(
    const float* __restrict__ X,
    const ushort_t* __restrict__ w1, const ushort_t* __restrict__ wih,
    const ushort_t* __restrict__ wcs, const ushort_t* __restrict__ whs,
    const float* __restrict__ bias,
    ushort_t* __restrict__ HN, ushort_t* __restrict__ CN,
    int* __restrict__ flags, int* __restrict__ claim, float* __restrict__ out)
{
  const int tid  = threadIdx.x;
  __shared__ int s_rank;

  // ---- single-XCD placement claim ----
  if (tid == 0) {
    int xcc;
    asm volatile("s_getreg_b32 %0, hwreg(HW_REG_XCC_ID)" : "=s"(xcc));
    xcc &= 7;
    int r = __hip_atomic_fetch_add(claim + xcc, 1, __ATOMIC_RELAXED, __HIP_MEMORY_SCOPE_AGENT);
    if (r == 31) {   // 32nd WG on this XCD: nominate it
      int exp = -1;
      __hip_atomic_compare_exchange_strong(claim + 8, &exp, xcc,
                                           __ATOMIC_RELAXED, __ATOMIC_RELAXED,
                                           __HIP_MEMORY_SCOPE_AGENT);
    }
    int w;
    while ((w = __hip_atomic_load(claim + 8, __ATOMIC_RELAXED, __HIP_MEMORY_SCOPE_AGENT)) < 0)
      __builtin_amdgcn_s_sleep(8);
    s_rank = (w == xcc && r < 32) ? r : -1;
  }
  __syncthreads();
  const int fb = s_rank;      // 0..31 feature block, or -1 = loser
  if (fb < 0) return;

  const int wid  = tid >> 6;
  const int lane = tid & 63;
  const int mh   = wid & 1;          // batch half
  const int ar   = lane & 15;
  const int ko   = (lane >> 4) << 3;

  __shared__ float s_tiles[12][16][20];   // padded rows (80B)

  // ---- per-thread elementwise mapping + bias in registers ----
  const int eb  = tid >> 3;          // batch row 0..31
  const int ejp = (tid & 7) * 2;     // column pair within the 16-col block
  const int emh = eb >> 4, ebr = eb & 15;
  float bI[2], bF[2], bG[2], bO[2];
  #pragma unroll
  for (int u = 0; u < 2; ++u) {
    bI[u] = bias[0 * 512 + fb * 16 + ejp + u];
    bF[u] = bias[1 * 512 + fb * 16 + ejp + u];
    bG[u] = bias[2 * 512 + fb * 16 + ejp + u];
    bO[u] = bias[3 * 512 + fb * 16 + ejp + u];
  }

  const int gtype0 = wid >> 1;            // i or f
  const int gtype1 = 2 + (wid >> 1);      // g or o

  // ---- state-pass B fragments: load ONCE into registers ----
  short8v bw0[16], bw1[16], bw2[16];
  {
    const ushort_t* p0 = w1 + ((size_t)(gtype0 * 512 + fb * 16 + ar)) * 512 + ko;
    const ushort_t* p1 = w1 + ((size_t)(gtype1 * 512 + fb * 16 + ar)) * 512 + ko;
    const ushort_t* p2 = ((wid < 2) ? wcs : whs) + ((size_t)(fb * 16 + ar)) * 512 + ko;
    #pragma unroll
    for (int kk = 0; kk < 16; ++kk) {
      bw0[kk] = *(const short8v*)(p0 + (size_t)kk * 32);
      bw1[kk] = *(const short8v*)(p1 + (size_t)kk * 32);
      bw2[kk] = *(const short8v*)(p2 + (size_t)kk * 32);
    }
  }

  const ushort_t* bx0_ = wih + ((size_t)(gtype0 * 512 + fb * 16 + ar)) * 512 + ko;
  const ushort_t* bx1_ = wih + ((size_t)(gtype1 * 512 + fb * 16 + ar)) * 512 + ko;
  const int arow_x = mh * 16 + ar;
  const int t0 = wid, t1 = wid + 4, t2 = wid + 8;

  for (int t = 0; t <= T_; ++t) {
    float4v acc0 = {0.f, 0.f, 0.f, 0.f};
    float4v acc1 = acc0, acc2 = acc0;

    // ---- prefetch output-pass X early ----
    float2v xo2 = {0.f, 0.f};
    if (t > 0)
      xo2 = *(const float2v*)&X[(size_t)eb * (T_ * 512) + (size_t)(t - 1) * 512 + fb * 16 + ejp];

    // ---- x-pass (state independent; weights/X stay L1/L2-hot) ----
    if (t < T_) {
      const float* xrow = X + (size_t)arow_x * (T_ * 512) + (size_t)t * 512 + ko;
      const ushort_t* bx0 = bx0_;
      const ushort_t* bx1 = bx1_;
      asm volatile("" : "+v"(bx0), "+v"(bx1));   // block LICM of 256 regs of x-weights
      #pragma unroll
      for (int kk = 0; kk < 16; ++kk) {
        const float* p = xrow + kk * 32;
        float4v xa = *(const float4v*)(p);
        float4v xb = *(const float4v*)(p + 4);
        uint4v ua = __builtin_bit_cast(uint4v, xa);
        uint4v ub = __builtin_bit_cast(uint4v, xb);
        uint4v pk;
        pk[0] = __builtin_amdgcn_perm(ua[1], ua[0], 0x07060302u);
        pk[1] = __builtin_amdgcn_perm(ua[3], ua[2], 0x07060302u);
        pk[2] = __builtin_amdgcn_perm(ub[1], ub[0], 0x07060302u);
        pk[3] = __builtin_amdgcn_perm(ub[3], ub[2], 0x07060302u);
        short8v a = __builtin_bit_cast(short8v, pk);
        short8v b0 = *(const short8v*)(bx0 + (size_t)kk * 32);
        short8v b1 = *(const short8v*)(bx1 + (size_t)kk * 32);
        acc0 = __builtin_amdgcn_mfma_f32_16x16x32_bf16(a, b0, acc0, 0, 0, 0);
        acc1 = __builtin_amdgcn_mfma_f32_16x16x32_bf16(a, b1, acc1, 0, 0, 0);
      }
    }

    // ---- poll packed flags via shared-L2 loads ----
    if (t > 0) {
      const int* fp = flags + (lane & 31);
      while (true) {
        int v;
        asm volatile("global_load_dword %0, %1, off sc0\n\ts_waitcnt vmcnt(0)"
                     : "=v"(v) : "v"(fp) : "memory");
        if (__all(v >= t)) break;
      }
      __builtin_amdgcn_sched_barrier(0);
    }

    // ---- state A-fragments: pipelined same-XCD L2 loads ----
    const int rs = (t + 3) & 3;
    const ushort_t* hb = HN + (size_t)rs * (32 * 512) + (size_t)arow_x * 512 + ko;
    short8v hfrag[16];
    #pragma unroll
    for (int kk = 0; kk < 16; ++kk)
      hfrag[kk] = ld_l2_16(hb + (size_t)kk * 32);
    short8v cfrag[16];
    if (wid < 2) {
      const ushort_t* cb = CN + (size_t)rs * (32 * 512) + (size_t)arow_x * 512 + ko;
      #pragma unroll
      for (int kk = 0; kk < 16; ++kk)
        cfrag[kk] = ld_l2_16(cb + (size_t)kk * 32);
    }
    asm volatile("s_waitcnt vmcnt(0)" ::: "memory");
    __builtin_amdgcn_sched_barrier(0);     // MFMAs must not hoist above the wait

    // ---- state MFMA: A and B from registers ----
    #pragma unroll
    for (int kk = 0; kk < 16; ++kk) {
      acc0 = __builtin_amdgcn_mfma_f32_16x16x32_bf16(hfrag[kk], bw0[kk], acc0, 0, 0, 0);
      acc1 = __builtin_amdgcn_mfma_f32_16x16x32_bf16(hfrag[kk], bw1[kk], acc1, 0, 0, 0);
      short8v a2 = (wid < 2) ? cfrag[kk] : hfrag[kk];
      acc2 = __builtin_amdgcn_mfma_f32_16x16x32_bf16(a2, bw2[kk], acc2, 0, 0, 0);
    }

    __syncthreads();   // barrier1: prev iteration's s_tiles readers done

    {
      const int rb = (lane >> 4) << 2, cc = lane & 15;
      #pragma unroll
      for (int r = 0; r < 4; ++r) {
        s_tiles[t0][rb + r][cc] = acc0[r];
        s_tiles[t1][rb + r][cc] = acc1[r];
        s_tiles[t2][rb + r][cc] = acc2[r];
      }
    }
    __syncthreads();   // barrier2: tiles visible

    // ---- elementwise cell update + same-XCD L2 state store ----
    if (t < T_) {
      unsigned hpk = 0, cpk = 0;
      #pragma unroll
      for (int u = 0; u < 2; ++u) {
        int j = ejp + u;
        float iv  = s_tiles[0 + emh][ebr][j] + bI[u];
        float fv  = s_tiles[2 + emh][ebr][j] + bF[u];
        float gv  = s_tiles[4 + emh][ebr][j] + bG[u];
        float ov  = s_tiles[6 + emh][ebr][j] + bO[u];
        float c2p = s_tiles[8 + emh][ebr][j];
        float cnv = sigm(fv) * c2p + sigm(iv) * tanh_(gv);
        float hnv = sigm(ov) * tanh_(cnv);
        hpk |= ((unsigned)f2bf(hnv)) << (16 * u);
        cpk |= ((unsigned)f2bf(cnv)) << (16 * u);
      }
      size_t uso = (size_t)(t & 3) * (32 * 512) + (size_t)eb * 512 + fb * 16 + ejp;
      st_l2_u32(HN + uso, hpk);
      st_l2_u32(CN + uso, cpk);
    }
    // drain own stores (asm stores are untracked by compiler waitcnt!)
    asm volatile("s_waitcnt vmcnt(0)" ::: "memory");
    __syncthreads();   // barrier3: all threads' state stores in L2
    if (t < T_ && tid == 0)
      st_l2_u32(flags + fb, (unsigned)(t + 1));

    // ---- output for step t-1 (after signaling) ----
    if (t > 0) {
      float ov2[2];
      #pragma unroll
      for (int u = 0; u < 2; ++u) {
        int j = ejp + u;
        float c2p = s_tiles[8 + emh][ebr][j];
        float h2p = s_tiles[10 + emh][ebr][j];
        float att = tanh_(h2p + c2p);
        float xo  = (u ? xo2[1] : xo2[0]);
        float o1  = tanh_(att + xo);
        ov2[u] = xo + tanh_(o1);
      }
      float2v o2; o2[0] = ov2[0]; o2[1] = ov2[1];
      *(float2v*)&out[(size_t)eb * (T_ * 512) + (size_t)(t - 1) * 512 + fb * 16 + ejp] = o2;
    }
  }
}

extern "C" void kernel_launch(void* const* d_in, const int* in_sizes, int n_in,
                              void* d_out, int out_size, void* d_ws, size_t ws_size,
                              hipStream_t stream) {
  const float* X   = (const float*)d_in[0];
  const float* Wih = (const float*)d_in[1];
  const float* Whh = (const float*)d_in[2];
  const float* bih = (const float*)d_in[3];
  const float* bhh = (const float*)d_in[4];
  const float* Whs = (const float*)d_in[5];
  const float* Wcs = (const float*)d_in[6];

  char* ws = (char*)d_ws;
  ushort_t* w1_bf  = (ushort_t*)(ws + 0);        // 2,097,152 B
  ushort_t* wih_bf = (ushort_t*)(ws + 2097152);  // 2,097,152 B
  ushort_t* wcs_bf = (ushort_t*)(ws + 4194304);  //   524,288 B
  ushort_t* whs_bf = (ushort_t*)(ws + 4718592);  //   524,288 B
  float*    bias   = (float*)   (ws + 5242880);  //     8,192 B
  ushort_t* HN     = (ushort_t*)(ws + 5251072);  //   131,072 B (4-slot ring)
  ushort_t* CN     = (ushort_t*)(ws + 5382144);  //   131,072 B
  int*      flags  = (int*)     (ws + 5513216);  //       128 B (packed int[32])
  int*      claim  = (int*)     (ws + 5513344);  //        36 B (ctr[8] + winner)
  if (ws_size < (size_t)5513504) return;

  k_prep_w1<<<4096, 256, 0, stream>>>(Whh, Whs, w1_bf);
  k_prep_misc<<<2048, 256, 0, stream>>>(Wih, Wcs, Whs, bih, bhh,
                                        wih_bf, wcs_bf, whs_bf, bias, HN, CN, flags, claim);
  k_lstm<<<512, 256, 0, stream>>>(X, w1_bf, wih_bf, wcs_bf, whs_bf, bias,
                                  HN, CN, flags, claim, (float*)d_out);
}

// Round 7
// 11465.388 us; speedup vs baseline: 2.7369x; 2.7369x over previous
//
#include <hip/hip_runtime.h>

#define T_   2048
#define NWG  32

typedef float  float4v __attribute__((ext_vector_type(4)));
typedef float  float2v __attribute__((ext_vector_type(2)));
typedef short  short8v __attribute__((ext_vector_type(8)));
typedef short  short4v __attribute__((ext_vector_type(4)));
typedef unsigned uint4v __attribute__((ext_vector_type(4)));
typedef unsigned short ushort_t;

__device__ __forceinline__ ushort_t f2bf(float f) {
  union { float f; unsigned u; } v; v.f = f;
  unsigned r = (v.u + 0x7FFFu + ((v.u >> 16) & 1u)) >> 16;  // RTN
  return (ushort_t)r;
}
__device__ __forceinline__ float bf2f(short s) {
  union { unsigned u; float f; } v; v.u = ((unsigned)(unsigned short)s) << 16;
  return v.f;
}
__device__ __forceinline__ float sigm(float x) {
  x = fmaxf(x, -30.f);
  return __fdividef(1.f, 1.f + __expf(-x));
}
__device__ __forceinline__ float tanh_(float x) {
  x = fminf(fmaxf(x, -15.f), 15.f);
  float e = __expf(2.f * x);
  return (e - 1.f) * __fdividef(1.f, e + 1.f);
}

// Coherence-point 16B load (bypass L1+L2, no cache-wide invalidate). Plain-
// pipelined; caller must s_waitcnt vmcnt(0) before consuming.
__device__ __forceinline__ short8v ld_coh16(const ushort_t* p) {
  short8v r;
  asm volatile("global_load_dwordx4 %0, %1, off sc0 sc1" : "=v"(r) : "v"(p));
  return r;
}

// W1[n,k] = sum_j W_hh[n,j] * W_hs[j,k]   (fold: h2 @ W_hh^T == h_new @ W1^T)
__global__ void k_prep_w1(const float* __restrict__ Whh, const float* __restrict__ Whs,
                          ushort_t* __restrict__ w1) {
  int idx = blockIdx.x * 256 + threadIdx.x;
  if (idx >= 2048 * 512) return;
  int n = idx >> 9, k = idx & 511;
  const float* whr = Whh + (size_t)n * 512;
  const float* wsk = Whs + k;
  float s = 0.f;
  #pragma unroll 8
  for (int j = 0; j < 512; ++j) s += whr[j] * wsk[(size_t)j * 512];
  w1[idx] = f2bf(s);
}

__global__ void k_prep_misc(const float* __restrict__ Wih, const float* __restrict__ Wcs,
                            const float* __restrict__ Whs, const float* __restrict__ bih,
                            const float* __restrict__ bhh,
                            ushort_t* __restrict__ wih_bf, ushort_t* __restrict__ wcs_bf,
                            ushort_t* __restrict__ whs_bf, float* __restrict__ bias,
                            ushort_t* __restrict__ HN, ushort_t* __restrict__ CN,
                            int* __restrict__ flags) {
  const int total = 1048576 + 262144 + 262144 + 2048 + 16384 + 16384 + 512;
  for (int i = blockIdx.x * blockDim.x + threadIdx.x; i < total; i += gridDim.x * blockDim.x) {
    int r = i;
    if (r < 1048576) { wih_bf[r] = f2bf(Wih[r]); continue; }
    r -= 1048576;
    if (r < 262144)  { wcs_bf[r] = f2bf(Wcs[r]); continue; }
    r -= 262144;
    if (r < 262144)  { whs_bf[r] = f2bf(Whs[r]); continue; }
    r -= 262144;
    if (r < 2048)    { bias[r] = bih[r] + bhh[r]; continue; }
    r -= 2048;
    if (r < 16384)   { HN[3 * 16384 + r] = 0; continue; }   // zero ring slot 3 (state t=-1)
    r -= 16384;
    if (r < 16384)   { CN[3 * 16384 + r] = 0; continue; }
    r -= 16384;
    flags[r] = 0;   // 512 ints: 64B-padded flag slots
  }
}

// G[t][fb][gate][col][batch] = (X_t @ Wih^T) in MFMA C-fragment order, bf16.
// bid = tg*32 + fb (tg-major: the 32 fb-blocks sharing X_t are adjacent ->
// spread round-robin over XCDs, each XCD's L2 fetches X_t once).
// Wave wid computes t = tg*4 + wid.
__global__ __launch_bounds__(256) void k_gemm_g(
    const float* __restrict__ X, const ushort_t* __restrict__ wih,
    ushort_t* __restrict__ G) {
  const int bid = blockIdx.x;
  const int fb  = bid & 31;
  const int tg  = bid >> 5;
  const int wid = threadIdx.x >> 6;
  const int lane = threadIdx.x & 63;
  const int t   = tg * 4 + wid;
  const int ar  = lane & 15;
  const int ko  = (lane >> 4) << 3;

  float4v acc[2][4];
  #pragma unroll
  for (int mh = 0; mh < 2; ++mh)
    #pragma unroll
    for (int cg = 0; cg < 4; ++cg)
      acc[mh][cg] = float4v{0.f, 0.f, 0.f, 0.f};

  #pragma unroll 4
  for (int kk = 0; kk < 16; ++kk) {
    short8v a[2];
    #pragma unroll
    for (int mh = 0; mh < 2; ++mh) {
      const float* p = X + (size_t)(mh * 16 + ar) * (T_ * 512) + (size_t)t * 512 + kk * 32 + ko;
      float4v xa = *(const float4v*)(p);
      float4v xb = *(const float4v*)(p + 4);
      uint4v ua = __builtin_bit_cast(uint4v, xa);
      uint4v ub = __builtin_bit_cast(uint4v, xb);
      uint4v pk;
      pk[0] = __builtin_amdgcn_perm(ua[1], ua[0], 0x07060302u);
      pk[1] = __builtin_amdgcn_perm(ua[3], ua[2], 0x07060302u);
      pk[2] = __builtin_amdgcn_perm(ub[1], ub[0], 0x07060302u);
      pk[3] = __builtin_amdgcn_perm(ub[3], ub[2], 0x07060302u);
      a[mh] = __builtin_bit_cast(short8v, pk);
    }
    #pragma unroll
    for (int cg = 0; cg < 4; ++cg) {
      short8v b = *(const short8v*)(wih + ((size_t)(cg * 512 + fb * 16 + ar)) * 512 + kk * 32 + ko);
      acc[0][cg] = __builtin_amdgcn_mfma_f32_16x16x32_bf16(a[0], b, acc[0][cg], 0, 0, 0);
      acc[1][cg] = __builtin_amdgcn_mfma_f32_16x16x32_bf16(a[1], b, acc[1][cg], 0, 0, 0);
    }
  }

  const size_t base = ((size_t)t * 32 + fb) * 2048;
  #pragma unroll
  for (int mh = 0; mh < 2; ++mh)
    #pragma unroll
    for (int cg = 0; cg < 4; ++cg) {
      short4v s;
      #pragma unroll
      for (int r = 0; r < 4; ++r) s[r] = (short)f2bf(acc[mh][cg][r]);
      *(short4v*)(G + base + cg * 512 + ar * 32 + mh * 16 + ((lane >> 4) << 2)) = s;
    }
}

// ===== persistent kernel, PRE path: gate x-contribution read from G =====
// Round-4 chassis (plain 32-WG grid, agent-scope padded flags, sc0sc1 state
// loads) with the x-pass deleted and a 1-step-ahead G prefetch instead.
__global__ __launch_bounds__(256, 1) void k_lstm_pre(
    const float* __restrict__ X,
    const ushort_t* __restrict__ w1,
    const ushort_t* __restrict__ wcs, const ushort_t* __restrict__ whs,
    const float* __restrict__ bias, const ushort_t* __restrict__ G,
    ushort_t* __restrict__ HN, ushort_t* __restrict__ CN,
    int* __restrict__ flags, float* __restrict__ out)
{
  const int fb   = blockIdx.x;
  const int tid  = threadIdx.x;
  const int wid  = tid >> 6;
  const int lane = tid & 63;
  const int mh   = wid & 1;
  const int ar   = lane & 15;
  const int ko   = (lane >> 4) << 3;

  __shared__ float s_tiles[12][16][20];

  const int eb  = tid >> 3;
  const int ejp = (tid & 7) * 2;
  const int emh = eb >> 4, ebr = eb & 15;
  float bI[2], bF[2], bG[2], bO[2];
  #pragma unroll
  for (int u = 0; u < 2; ++u) {
    bI[u] = bias[0 * 512 + fb * 16 + ejp + u];
    bF[u] = bias[1 * 512 + fb * 16 + ejp + u];
    bG[u] = bias[2 * 512 + fb * 16 + ejp + u];
    bO[u] = bias[3 * 512 + fb * 16 + ejp + u];
  }

  const int gtype0 = wid >> 1;
  const int gtype1 = 2 + (wid >> 1);

  // state-pass B fragments: load ONCE into registers
  short8v bw0[16], bw1[16], bw2[16];
  {
    const ushort_t* p0 = w1 + ((size_t)(gtype0 * 512 + fb * 16 + ar)) * 512 + ko;
    const ushort_t* p1 = w1 + ((size_t)(gtype1 * 512 + fb * 16 + ar)) * 512 + ko;
    const ushort_t* p2 = ((wid < 2) ? wcs : whs) + ((size_t)(fb * 16 + ar)) * 512 + ko;
    #pragma unroll
    for (int kk = 0; kk < 16; ++kk) {
      bw0[kk] = *(const short8v*)(p0 + (size_t)kk * 32);
      bw1[kk] = *(const short8v*)(p1 + (size_t)kk * 32);
      bw2[kk] = *(const short8v*)(p2 + (size_t)kk * 32);
    }
  }

  const int arow_x = mh * 16 + ar;
  const int t0 = wid, t1 = wid + 4, t2 = wid + 8;
  const int glo = ((lane >> 4) << 2) + mh * 16 + ar * 32;   // per-lane G offset

  short4v gp0, gp1;
  {   // prologue prefetch for t=0
    const ushort_t* gb = G + (size_t)fb * 2048 + glo;
    gp0 = *(const short4v*)(gb + gtype0 * 512);
    gp1 = *(const short4v*)(gb + gtype1 * 512);
  }

  for (int t = 0; t <= T_; ++t) {
    // ---- prefetch output-pass X early ----
    float2v xo2 = {0.f, 0.f};
    if (t > 0)
      xo2 = *(const float2v*)&X[(size_t)eb * (T_ * 512) + (size_t)(t - 1) * 512 + fb * 16 + ejp];

    // ---- poll (agent-scope relaxed atomic, padded flag slots) ----
    if (t > 0) {
      while (true) {
        int v = (lane < NWG)
              ? __hip_atomic_load(flags + lane * 16, __ATOMIC_RELAXED, __HIP_MEMORY_SCOPE_AGENT)
              : t;
        if (__all(v >= t)) break;
      }
      __builtin_amdgcn_sched_barrier(0);
    }

    // ---- state A-fragments: pipelined coherence-point loads ----
    const int rs = (t + 3) & 3;
    const ushort_t* hb = HN + (size_t)rs * (32 * 512) + (size_t)arow_x * 512 + ko;
    short8v hfrag[16];
    #pragma unroll
    for (int kk = 0; kk < 16; ++kk)
      hfrag[kk] = ld_coh16(hb + (size_t)kk * 32);
    short8v cfrag[16];
    if (wid < 2) {
      const ushort_t* cb = CN + (size_t)rs * (32 * 512) + (size_t)arow_x * 512 + ko;
      #pragma unroll
      for (int kk = 0; kk < 16; ++kk)
        cfrag[kk] = ld_coh16(cb + (size_t)kk * 32);
    }

    // ---- init gate accumulators from prefetched G (overlaps the load wait) ----
    float4v acc0, acc1, acc2;
    #pragma unroll
    for (int r = 0; r < 4; ++r) {
      acc0[r] = bf2f(gp0[r]);
      acc1[r] = bf2f(gp1[r]);
      acc2[r] = 0.f;
    }

    asm volatile("s_waitcnt vmcnt(0)" ::: "memory");
    __builtin_amdgcn_sched_barrier(0);     // MFMAs must not hoist above the wait

    // ---- state MFMA: A and B from registers ----
    #pragma unroll
    for (int kk = 0; kk < 16; ++kk) {
      acc0 = __builtin_amdgcn_mfma_f32_16x16x32_bf16(hfrag[kk], bw0[kk], acc0, 0, 0, 0);
      acc1 = __builtin_amdgcn_mfma_f32_16x16x32_bf16(hfrag[kk], bw1[kk], acc1, 0, 0, 0);
      short8v a2 = (wid < 2) ? cfrag[kk] : hfrag[kk];
      acc2 = __builtin_amdgcn_mfma_f32_16x16x32_bf16(a2, bw2[kk], acc2, 0, 0, 0);
    }

    __syncthreads();   // barrier1: prev iteration's s_tiles readers done

    {
      const int rb = (lane >> 4) << 2, cc = lane & 15;
      #pragma unroll
      for (int r = 0; r < 4; ++r) {
        s_tiles[t0][rb + r][cc] = acc0[r];
        s_tiles[t1][rb + r][cc] = acc1[r];
        s_tiles[t2][rb + r][cc] = acc2[r];
      }
    }
    __syncthreads();   // barrier2: tiles visible

    // ---- elementwise cell update + agent-scope state store ----
    if (t < T_) {
      unsigned hpk = 0, cpk = 0;
      #pragma unroll
      for (int u = 0; u < 2; ++u) {
        int j = ejp + u;
        float iv  = s_tiles[0 + emh][ebr][j] + bI[u];
        float fv  = s_tiles[2 + emh][ebr][j] + bF[u];
        float gv  = s_tiles[4 + emh][ebr][j] + bG[u];
        float ov  = s_tiles[6 + emh][ebr][j] + bO[u];
        float c2p = s_tiles[8 + emh][ebr][j];
        float cnv = sigm(fv) * c2p + sigm(iv) * tanh_(gv);
        float hnv = sigm(ov) * tanh_(cnv);
        hpk |= ((unsigned)f2bf(hnv)) << (16 * u);
        cpk |= ((unsigned)f2bf(cnv)) << (16 * u);
      }
      size_t uso = (size_t)(t & 3) * (32 * 512) + (size_t)eb * 512 + fb * 16 + ejp;
      __hip_atomic_store((unsigned*)(HN + uso), hpk,
                         __ATOMIC_RELAXED, __HIP_MEMORY_SCOPE_AGENT);
      __hip_atomic_store((unsigned*)(CN + uso), cpk,
                         __ATOMIC_RELAXED, __HIP_MEMORY_SCOPE_AGENT);
    }
    __syncthreads();   // barrier3: vmcnt(0) drains the stores before the flag
    if (t < T_ && tid == 0)
      __hip_atomic_store(flags + fb * 16, t + 1, __ATOMIC_RELAXED, __HIP_MEMORY_SCOPE_AGENT);

    // ---- prefetch next step's G fragment (in flight across next poll) ----
    if (t + 1 < T_) {
      const ushort_t* gb = G + ((size_t)((t + 1) * 32 + fb)) * 2048 + glo;
      gp0 = *(const short4v*)(gb + gtype0 * 512);
      gp1 = *(const short4v*)(gb + gtype1 * 512);
    }

    // ---- output for step t-1 (after signaling) ----
    if (t > 0) {
      float ov2[2];
      #pragma unroll
      for (int u = 0; u < 2; ++u) {
        int j = ejp + u;
        float c2p = s_tiles[8 + emh][ebr][j];
        float h2p = s_tiles[10 + emh][ebr][j];
        float att = tanh_(h2p + c2p);
        float xo  = (u ? xo2[1] : xo2[0]);
        float o1  = tanh_(att + xo);
        ov2[u] = xo + tanh_(o1);
      }
      float2v o2; o2[0] = ov2[0]; o2[1] = ov2[1];
      *(float2v*)&out[(size_t)eb * (T_ * 512) + (size_t)(t - 1) * 512 + fb * 16 + ejp] = o2;
    }
  }
}

// ===== fallback: verbatim round-4 kernel (in-loop x-pass), proven to run =====
__global__ __launch_bounds__(256, 1) void k_lstm_fb(
    const float* __restrict__ X,
    const ushort_t* __restrict__ w1, const ushort_t* __restrict__ wih,
    const ushort_t* __restrict__ wcs, const ushort_t* __restrict__ whs,
    const float* __restrict__ bias,
    ushort_t* __restrict__ HN, ushort_t* __restrict__ CN,
    int* __restrict__ flags, float* __restrict__ out)
{
  const int fb   = blockIdx.x;
  const int tid  = threadIdx.x;
  const int wid  = tid >> 6;
  const int lane = tid & 63;
  const int mh   = wid & 1;
  const int ar   = lane & 15;
  const int ko   = (lane >> 4) << 3;

  __shared__ float s_tiles[12][16][20];

  const int eb  = tid >> 3;
  const int ejp = (tid & 7) * 2;
  const int emh = eb >> 4, ebr = eb & 15;
  float bI[2], bF[2], bG[2], bO[2];
  #pragma unroll
  for (int u = 0; u < 2; ++u) {
    bI[u] = bias[0 * 512 + fb * 16 + ejp + u];
    bF[u] = bias[1 * 512 + fb * 16 + ejp + u];
    bG[u] = bias[2 * 512 + fb * 16 + ejp + u];
    bO[u] = bias[3 * 512 + fb * 16 + ejp + u];
  }

  const int gtype0 = wid >> 1;
  const int gtype1 = 2 + (wid >> 1);

  short8v bw0[16], bw1[16], bw2[16];
  {
    const ushort_t* p0 = w1 + ((size_t)(gtype0 * 512 + fb * 16 + ar)) * 512 + ko;
    const ushort_t* p1 = w1 + ((size_t)(gtype1 * 512 + fb * 16 + ar)) * 512 + ko;
    const ushort_t* p2 = ((wid < 2) ? wcs : whs) + ((size_t)(fb * 16 + ar)) * 512 + ko;
    #pragma unroll
    for (int kk = 0; kk < 16; ++kk) {
      bw0[kk] = *(const short8v*)(p0 + (size_t)kk * 32);
      bw1[kk] = *(const short8v*)(p1 + (size_t)kk * 32);
      bw2[kk] = *(const short8v*)(p2 + (size_t)kk * 32);
    }
  }

  const ushort_t* bx0_ = wih + ((size_t)(gtype0 * 512 + fb * 16 + ar)) * 512 + ko;
  const ushort_t* bx1_ = wih + ((size_t)(gtype1 * 512 + fb * 16 + ar)) * 512 + ko;
  const int arow_x = mh * 16 + ar;
  const int t0 = wid, t1 = wid + 4, t2 = wid + 8;

  for (int t = 0; t <= T_; ++t) {
    float4v acc0 = {0.f, 0.f, 0.f, 0.f};
    float4v acc1 = acc0, acc2 = acc0;

    float2v xo2 = {0.f, 0.f};
    if (t > 0)
      xo2 = *(const float2v*)&X[(size_t)eb * (T_ * 512) + (size_t)(t - 1) * 512 + fb * 16 + ejp];

    if (t < T_) {
      const float* xrow = X + (size_t)arow_x * (T_ * 512) + (size_t)t * 512 + ko;
      const ushort_t* bx0 = bx0_;
      const ushort_t* bx1 = bx1_;
      asm volatile("" : "+v"(bx0), "+v"(bx1));
      #pragma unroll
      for (int kk = 0; kk < 16; ++kk) {
        const float* p = xrow + kk * 32;
        float4v xa = *(const float4v*)(p);
        float4v xb = *(const float4v*)(p + 4);
        uint4v ua = __builtin_bit_cast(uint4v, xa);
        uint4v ub = __builtin_bit_cast(uint4v, xb);
        uint4v pk;
        pk[0] = __builtin_amdgcn_perm(ua[1], ua[0], 0x07060302u);
        pk[1] = __builtin_amdgcn_perm(ua[3], ua[2], 0x07060302u);
        pk[2] = __builtin_amdgcn_perm(ub[1], ub[0], 0x07060302u);
        pk[3] = __builtin_amdgcn_perm(ub[3], ub[2], 0x07060302u);
        short8v a = __builtin_bit_cast(short8v, pk);
        short8v b0 = *(const short8v*)(bx0 + (size_t)kk * 32);
        short8v b1 = *(const short8v*)(bx1 + (size_t)kk * 32);
        acc0 = __builtin_amdgcn_mfma_f32_16x16x32_bf16(a, b0, acc0, 0, 0, 0);
        acc1 = __builtin_amdgcn_mfma_f32_16x16x32_bf16(a, b1, acc1, 0, 0, 0);
      }
    }

    if (t > 0) {
      while (true) {
        int v = (lane < NWG)
              ? __hip_atomic_load(flags + lane * 16, __ATOMIC_RELAXED, __HIP_MEMORY_SCOPE_AGENT)
              : t;
        if (__all(v >= t)) break;
      }
      __builtin_amdgcn_sched_barrier(0);
    }

    const int rs = (t + 3) & 3;
    const ushort_t* hb = HN + (size_t)rs * (32 * 512) + (size_t)arow_x * 512 + ko;
    short8v hfrag[16];
    #pragma unroll
    for (int kk = 0; kk < 16; ++kk)
      hfrag[kk] = ld_coh16(hb + (size_t)kk * 32);
    short8v cfrag[16];
    if (wid < 2) {
      const ushort_t* cb = CN + (size_t)rs * (32 * 512) + (size_t)arow_x * 512 + ko;
      #pragma unroll
      for (int kk = 0; kk < 16; ++kk)
        cfrag[kk] = ld_coh16(cb + (size_t)kk * 32);
    }
    asm volatile("s_waitcnt vmcnt(0)" ::: "memory");
    __builtin_amdgcn_sched_barrier(0);

    #pragma unroll
    for (int kk = 0; kk < 16; ++kk) {
      acc0 = __builtin_amdgcn_mfma_f32_16x16x32_bf16(hfrag[kk], bw0[kk], acc0, 0, 0, 0);
      acc1 = __builtin_amdgcn_mfma_f32_16x16x32_bf16(hfrag[kk], bw1[kk], acc1, 0, 0, 0);
      short8v a2 = (wid < 2) ? cfrag[kk] : hfrag[kk];
      acc2 = __builtin_amdgcn_mfma_f32_16x16x32_bf16(a2, bw2[kk], acc2, 0, 0, 0);
    }

    __syncthreads();

    {
      const int rb = (lane >> 4) << 2, cc = lane & 15;
      #pragma unroll
      for (int r = 0; r < 4; ++r) {
        s_tiles[t0][rb + r][cc] = acc0[r];
        s_tiles[t1][rb + r][cc] = acc1[r];
        s_tiles[t2][rb + r][cc] = acc2[r];
      }
    }
    __syncthreads();

    if (t < T_) {
      unsigned hpk = 0, cpk = 0;
      #pragma unroll
      for (int u = 0; u < 2; ++u) {
        int j = ejp + u;
        float iv  = s_tiles[0 + emh][ebr][j] + bI[u];
        float fv  = s_tiles[2 + emh][ebr][j] + bF[u];
        float gv  = s_tiles[4 + emh][ebr][j] + bG[u];
        float ov  = s_tiles[6 + emh][ebr][j] + bO[u];
        float c2p = s_tiles[8 + emh][ebr][j];
        float cnv = sigm(fv) * c2p + sigm(iv) * tanh_(gv);
        float hnv = sigm(ov) * tanh_(cnv);
        hpk |= ((unsigned)f2bf(hnv)) << (16 * u);
        cpk |= ((unsigned)f2bf(cnv)) << (16 * u);
      }
      size_t uso = (size_t)(t & 3) * (32 * 512) + (size_t)eb * 512 + fb * 16 + ejp;
      __hip_atomic_store((unsigned*)(HN + uso), hpk,
                         __ATOMIC_RELAXED, __HIP_MEMORY_SCOPE_AGENT);
      __hip_atomic_store((unsigned*)(CN + uso), cpk,
                         __ATOMIC_RELAXED, __HIP_MEMORY_SCOPE_AGENT);
    }
    __syncthreads();
    if (t < T_ && tid == 0)
      __hip_atomic_store(flags + fb * 16, t + 1, __ATOMIC_RELAXED, __HIP_MEMORY_SCOPE_AGENT);

    if (t > 0) {
      float ov2[2];
      #pragma unroll
      for (int u = 0; u < 2; ++u) {
        int j = ejp + u;
        float c2p = s_tiles[8 + emh][ebr][j];
        float h2p = s_tiles[10 + emh][ebr][j];
        float att = tanh_(h2p + c2p);
        float xo  = (u ? xo2[1] : xo2[0]);
        float o1  = tanh_(att + xo);
        ov2[u] = xo + tanh_(o1);
      }
      float2v o2; o2[0] = ov2[0]; o2[1] = ov2[1];
      *(float2v*)&out[(size_t)eb * (T_ * 512) + (size_t)(t - 1) * 512 + fb * 16 + ejp] = o2;
    }
  }
}

extern "C" void kernel_launch(void* const* d_in, const int* in_sizes, int n_in,
                              void* d_out, int out_size, void* d_ws, size_t ws_size,
                              hipStream_t stream) {
  const float* X   = (const float*)d_in[0];
  const float* Wih = (const float*)d_in[1];
  const float* Whh = (const float*)d_in[2];
  const float* bih = (const float*)d_in[3];
  const float* bhh = (const float*)d_in[4];
  const float* Whs = (const float*)d_in[5];
  const float* Wcs = (const float*)d_in[6];

  char* ws = (char*)d_ws;
  ushort_t* w1_bf  = (ushort_t*)(ws + 0);        // 2,097,152 B
  ushort_t* wih_bf = (ushort_t*)(ws + 2097152);  // 2,097,152 B
  ushort_t* wcs_bf = (ushort_t*)(ws + 4194304);  //   524,288 B
  ushort_t* whs_bf = (ushort_t*)(ws + 4718592);  //   524,288 B
  float*    bias   = (float*)   (ws + 5242880);  //     8,192 B
  ushort_t* HN     = (ushort_t*)(ws + 5251072);  //   131,072 B (4-slot ring)
  ushort_t* CN     = (ushort_t*)(ws + 5382144);  //   131,072 B
  int*      flags  = (int*)     (ws + 5513216);  //     2,048 B (64B-padded)
  ushort_t* G      = (ushort_t*)(ws + 5515264);  // 268,435,456 B (optional)
  if (ws_size < (size_t)5515264) return;
  const bool pre = ws_size >= (size_t)5515264 + (size_t)268435456;

  k_prep_w1<<<4096, 256, 0, stream>>>(Whh, Whs, w1_bf);
  k_prep_misc<<<2048, 256, 0, stream>>>(Wih, Wcs, Whs, bih, bhh,
                                        wih_bf, wcs_bf, whs_bf, bias, HN, CN, flags);
  if (pre) {
    k_gemm_g<<<16384, 256, 0, stream>>>(X, wih_bf, G);
    k_lstm_pre<<<NWG, 256, 0, stream>>>(X, w1_bf, wcs_bf, whs_bf, bias, G,
                                        HN, CN, flags, (float*)d_out);
  } else {
    k_lstm_fb<<<NWG, 256, 0, stream>>>(X, w1_bf, wih_bf, wcs_bf, whs_bf, bias,
                                       HN, CN, flags, (float*)d_out);
  }
}